// Round 10
// baseline (5120.330 us; speedup 1.0000x reference)
//
#include <hip/hip_runtime.h>
#include <hip/hip_fp16.h>

#define HDIM 256
#define LSEQ 512
#define PRED 96
#define NTHR 512  // 8 waves, 2/SIMD; wave w owns h-rows [32w, 32w+32)

typedef _Float16 f16x8 __attribute__((ext_vector_type(8)));
typedef _Float16 f16x4 __attribute__((ext_vector_type(4)));
typedef float f32x4 __attribute__((ext_vector_type(4)));
typedef unsigned int u32;

// prepacked f16 W_hh fragments: [layer 3][wave 8][kt 8][tau 6][lane 64][8]
__device__ __align__(16) _Float16 wpk_g[3 * 196608];  // 1.15 MB

__device__ __forceinline__ float sigm(float x) { return 1.f / (1.f + __expf(-x)); }
__device__ __forceinline__ float tanh_(float x) { float t = __expf(2.f * x); return 1.f - 2.f / (t + 1.f); }
__device__ __forceinline__ float dppx1(float v) {
  return __builtin_bit_cast(float, __builtin_amdgcn_update_dpp(
      0, __builtin_bit_cast(int, v), 0xB1, 0xF, 0xF, true));
}

// One batch column per block, 256 blocks, 8 waves = 2/SIMD. Weights streamed
// from L2 (wpk_g) via a rolling 4-buffer pipeline.
// R10 discipline (R9 flaky: 2.44e-3 one run, 468 another => residual race in
// the in-flight-across-barrier vmem class): FULL-DRAIN barriers (vmcnt0 +
// lgkmcnt0) and vmcnt(0)-only waits — nothing rides across a barrier; no
// counted-vmcnt bookkeeping. Volatile MFMAs; acc reads only after full
// stream + 64cy fence (R6/R7 lesson).
struct __align__(16) Smem {
  _Float16 h[2][2][256];   // [buf][hi/lo][row]: h split f16 hi+lo == f32
  float tw[3][256], tb[3][256], bnh[256], wo[256];
  float xv[LSEQ];
  float red[2][8];         // decoder partial sums, double-buffered
};

#define DECL8                                                                  \
  f32x4 ac[6];  /* 24 AGPR accumulators (tau = gate*2 + slot) */               \
  f32x4 zc;                                                                    \
  { f32x4 z4 = {0.f, 0.f, 0.f, 0.f}; asm("" : "=a"(zc) : "0"(z4)); }           \
  f16x8 wA[6], wB[6], wC[6], wD[6]; /* rolling weight buffers, 96 VGPR */

// stream 6 tile-fragments of k-slice KT (16B/lane, coalesced 1KB/wave)
#define LOADW(DST, KT)                                                         \
  { _Pragma("unroll") for (int tau = 0; tau < 6; ++tau)                        \
      DST[tau] = *(const f16x8*)(wbase + ((KT) * 6 + tau) * 512 + lane * 8); }

// volatile: pin MFMA program order
#define MMW_S(I, AF, B) asm volatile("v_mfma_f32_16x16x32_f16 %0, %1, %2, %3" : "=a"(ac[I]) : "v"(AF), "v"(B), "a"(zc));
#define MMW(I, AF, B)   asm volatile("v_mfma_f32_16x16x32_f16 %0, %1, %2, %0" : "+a"(ac[I]) : "v"(AF), "v"(B));
#define MM6_S(WF, B) MMW_S(0, WF[0], B) MMW_S(1, WF[1], B) MMW_S(2, WF[2], B)  \
                     MMW_S(3, WF[3], B) MMW_S(4, WF[4], B) MMW_S(5, WF[5], B)
#define MM6(WF, B)   MMW(0, WF[0], B) MMW(1, WF[1], B) MMW(2, WF[2], B)        \
                     MMW(3, WF[3], B) MMW(4, WF[4], B) MMW(5, WF[5], B)

// full vmem drain; memory clobber pins loads/stores to their side of it
#define VMW0 asm volatile("s_waitcnt vmcnt(0)" ::: "memory");

// MFMA->VALU(accvgpr_read) fence AFTER the full stream: 64 cy + sched pin.
#define FENCE                                                                  \
  asm volatile("s_nop 7\n\ts_nop 7\n\ts_nop 7\n\ts_nop 7\n\t"                  \
               "s_nop 7\n\ts_nop 7\n\ts_nop 7\n\ts_nop 7"                      \
               : "+a"(ac[0]), "+a"(ac[1]), "+a"(ac[2]),                        \
                 "+a"(ac[3]), "+a"(ac[4]), "+a"(ac[5]));                       \
  __builtin_amdgcn_sched_barrier(0);

// FULL-DRAIN barrier: no memory op of any kind crosses a step boundary.
#define BAR asm volatile("s_waitcnt vmcnt(0) lgkmcnt(0)\n\ts_barrier" ::: "memory")

#define SELG2(P, G)                                                            \
  { const f32x4 e0 = ac[2 * (G)], e1 = ac[2 * (G) + 1]; P = s1 ? e1 : e0; }
#define PSUM(P)                                                                \
  { P[0] += dppx1(P[0]); P[1] += dppx1(P[1]);                                  \
    P[2] += dppx1(P[2]); P[3] += dppx1(P[3]); }

#define LDH(OFF) (*(const f16x8*)(hp + (OFF)))

// D[768, hi|lo] = Whh*h, kt-major, 48 MFMA. wX consumed at group g, refilled
// for g+4; end-of-stream refills kt0-3 for the NEXT step (drained by BAR).
// __VA_ARGS__ = early-issue hook (phase 3's gi loads: issued before the first
// MFMA half, consumed after the full stream -> ~full-step latency cover).
#define MCORE8(PB, ...)                                                        \
  {                                                                            \
    const char* hp = hq + (PB) * 1024;                                         \
    f16x8 u0 = LDH(0), u1 = LDH(64), u2 = LDH(128), u3 = LDH(192);             \
    __VA_ARGS__                                                                \
    MM6_S(wA, u0) u0 = LDH(256); LOADW(wA, 4)                                  \
    MM6(wB, u1)   u1 = LDH(320); LOADW(wB, 5)                                  \
    MM6(wC, u2)   u2 = LDH(384); LOADW(wC, 6)                                  \
    MM6(wD, u3)   u3 = LDH(448); LOADW(wD, 7)                                  \
    VMW0                                                                       \
    MM6(wA, u0)   LOADW(wA, 0)                                                 \
    MM6(wB, u1)   LOADW(wB, 1)                                                 \
    MM6(wC, u2)   LOADW(wC, 2)                                                 \
    MM6(wD, u3)   LOADW(wD, 3)                                                 \
    FENCE                                                                      \
    SELG2(pr, 0) PSUM(pr)                                                      \
    SELG2(pz, 1) PSUM(pz)                                                      \
    SELG2(pn, 2) PSUM(pn)                                                      \
  }

// Gate math + h update for this lane's 4 rows; st lanes (n in {0,2}) store.
#define GTAIL8(GR, GZ, GN, RHOOK, STEXTRA)                                     \
  {                                                                            \
    const char* rh = hrow + pb * 1024;                                         \
    char* wh = hrow + (pb ^ 1) * 1024;                                         \
    const f16x4 hh = *(const f16x4*)rh;                                        \
    const f16x4 hl = *(const f16x4*)(rh + 512);                                \
    const f32x4 bn4 = *(const f32x4*)bnrow;                                    \
    f16x4 vh, vl;                                                              \
    _Pragma("unroll") for (int r = 0; r < 4; ++r) {                            \
      const float rr = sigm((GR)[r] + pr[r]);                                  \
      const float zz = sigm((GZ)[r] + pz[r]);                                  \
      const float nn = tanh_(fmaf(rr, pn[r] + bn4[r], (GN)[r]));               \
      const float ho = (float)hh[r] + (float)hl[r];                            \
      const float hv = fmaf(zz, ho - nn, nn);                                  \
      vh[r] = (_Float16)hv;                                                    \
      vl[r] = (_Float16)(hv - (float)vh[r]);                                   \
      RHOOK                                                                    \
    }                                                                          \
    if (st) {                                                                  \
      *(f16x4*)wh = vh;                                                        \
      *(f16x4*)(wh + 512) = vl;                                                \
      STEXTRA                                                                  \
    }                                                                          \
  }

#define LANE_GEOM8                                                             \
  const int tid = threadIdx.x;                                                 \
  const int w = tid >> 6, lane = tid & 63, n = lane & 15, q = lane >> 4;       \
  const int b = blockIdx.x;                                                    \
  const bool s1 = (n & 2) != 0;                                                \
  const bool st = (n & 13) == 0; /* n in {0,2}: unique (slot,q) storers */     \
  const int sg1 = (n >> 1) & 1;                                                \
  const int row = 32 * w + 16 * sg1 + 4 * q;                                   \
  const char* hq = (const char*)sm.h + (n & 1) * 512 + q * 16;                 \
  char* hrow = (char*)sm.h + row * 2;                                          \
  const char* bnrow = (const char*)sm.bnh + row * 4;

// ============ Kernel 0: prepack W_hh{0,1,d} into fragment order ==============
__global__ __launch_bounds__(256) void prep(const float* __restrict__ W0,
                                            const float* __restrict__ W1,
                                            const float* __restrict__ Wd) {
  const int idx = blockIdx.x * 256 + threadIdx.x;  // 288*256 = 73728 exactly
  const int lane = idx & 63;
  int t2 = idx >> 6;
  const int tau = t2 % 6; t2 /= 6;
  const int kt = t2 & 7;  t2 >>= 3;
  const int w = t2 & 7;   t2 >>= 3;
  const int L = t2;
  const float* W = (L == 0) ? W0 : ((L == 1) ? W1 : Wd);
  const int g = tau >> 1, s = tau & 1, n = lane & 15, q = lane >> 4;
  const int r = 256 * g + 32 * w + 16 * s + n;   // A row (m89/m91 layout)
  const int c = 32 * kt + 8 * q;                 // k = 32kt + 8q + i
  const float4 a0 = *(const float4*)(W + (size_t)r * HDIM + c);
  const float4 a1 = *(const float4*)(W + (size_t)r * HDIM + c + 4);
  f16x8 tf;
  tf[0] = (_Float16)a0.x; tf[1] = (_Float16)a0.y;
  tf[2] = (_Float16)a0.z; tf[3] = (_Float16)a0.w;
  tf[4] = (_Float16)a1.x; tf[5] = (_Float16)a1.y;
  tf[6] = (_Float16)a1.z; tf[7] = (_Float16)a1.w;
  *(f16x8*)(wpk_g + (size_t)L * 196608 + (size_t)w * 24576 +
            (kt * 6 + tau) * 512 + lane * 8) = tf;
}

// =================== Kernel 1: encoder GRU layer 0 ===========================
__global__ __attribute__((amdgpu_flat_work_group_size(NTHR, NTHR), amdgpu_waves_per_eu(2)))
void gru_l0(const float* __restrict__ x, const float* __restrict__ Wih0,
            const float* __restrict__ bih0, const float* __restrict__ bhh0,
            __half* __restrict__ ys) {
  __shared__ Smem sm;
  LANE_GEOM8
  DECL8
  const _Float16* wbase = wpk_g + (size_t)w * 24576;  // layer 0
  const char* twp = (const char*)sm.tw + row * 4;
  const char* tbp = (const char*)sm.tb + row * 4;

  sm.xv[tid] = x[(size_t)b * LSEQ + tid];
  if (tid < 256) {
#pragma unroll
    for (int g = 0; g < 3; ++g) {
      sm.tw[g][tid] = Wih0[256 * g + tid];
      sm.tb[g][tid] = bih0[256 * g + tid] + (g < 2 ? bhh0[256 * g + tid] : 0.f);
    }
    sm.bnh[tid] = bhh0[512 + tid];  // bhh_n: sits INSIDE the r-multiply
  }
  ((u32*)sm.h)[tid] = 0;            // zero buf0+buf1 hi/lo (2048 B)
  LOADW(wA, 0) LOADW(wB, 1) LOADW(wC, 2) LOADW(wD, 3)
  __syncthreads();                  // full drain: primed buffers resident

  __half* ysp = ys + (size_t)b * LSEQ * HDIM + row;
  int pb = 0;
#pragma unroll 1
  for (int t = 0; t < LSEQ; ++t) {
    const float xt = sm.xv[t];
    f32x4 pr, pz, pn;
    MCORE8(pb, ;)
    const f32x4 g_r = *(const f32x4*)twp * xt + *(const f32x4*)tbp;
    const f32x4 g_z = *(const f32x4*)(twp + 1024) * xt + *(const f32x4*)(tbp + 1024);
    const f32x4 g_n = *(const f32x4*)(twp + 2048) * xt + *(const f32x4*)(tbp + 2048);
    GTAIL8(g_r, g_z, g_n, ;, *(f16x4*)ysp = vh;)
    ysp += HDIM;
    pb ^= 1;
    BAR;
  }
}

// ===== Kernel 2: GI1 = ys0 @ W_ih1^T + (bih1 + bhh1_{r,z}) — MFMA GEMM ======
__global__ __launch_bounds__(256) void gemm_gi(
    const float* __restrict__ Wih1, const float* __restrict__ bih1,
    const float* __restrict__ bhh1, const __half* __restrict__ ys,
    __half* __restrict__ gi) {
  const int lane = threadIdx.x & 63;
  const int wv = threadIdx.x >> 6;
  const size_t bt0 = (size_t)blockIdx.x << 4;
  const int n = lane & 15, q = lane >> 4;

  f16x8 bfr[8];
  const __half* yrow = ys + (bt0 + n) * HDIM + q * 8;
#pragma unroll
  for (int kk = 0; kk < 8; ++kk) bfr[kk] = *(const f16x8*)(yrow + kk * 32);

#pragma unroll 1
  for (int mt = 0; mt < 12; ++mt) {
    const int j0 = (wv * 12 + mt) << 4;
    const float* arow = Wih1 + (size_t)(j0 + n) * HDIM + q * 8;
    f32x4 acc = {0.f, 0.f, 0.f, 0.f};
#pragma unroll
    for (int kk = 0; kk < 8; ++kk) {
      const float4 a0 = *(const float4*)(arow + kk * 32);
      const float4 a1 = *(const float4*)(arow + kk * 32 + 4);
      f16x8 af;
      af[0] = (_Float16)a0.x; af[1] = (_Float16)a0.y;
      af[2] = (_Float16)a0.z; af[3] = (_Float16)a0.w;
      af[4] = (_Float16)a1.x; af[5] = (_Float16)a1.y;
      af[6] = (_Float16)a1.z; af[7] = (_Float16)a1.w;
      acc = __builtin_amdgcn_mfma_f32_16x16x32_f16(af, bfr[kk], acc, 0, 0, 0);
    }
    const int jr = j0 + (q << 2);
    __half o4[4];
#pragma unroll
    for (int r2 = 0; r2 < 4; ++r2) {
      const float bb = bih1[jr + r2] + (j0 < 512 ? bhh1[jr + r2] : 0.f);
      o4[r2] = __float2half(acc[r2] + bb);
    }
    *(uint2*)(gi + (bt0 + n) * 768 + jr) = *(uint2*)o4;
  }
}

// ====== Kernel 3: encoder GRU layer 1 (gi-driven) + autoregressive decoder ===
// Single-buffered per-step gi load, issued at stream top inside MCORE8 and
// consumed after the full stream (~full-step latency cover, no cross-barrier
// in-flight state).
#define LOADGI(PF, T)                                                          \
  { const __half* gp = gi + ((size_t)b * LSEQ + (T)) * 768 + row;              \
    PF[0] = *(const uint2*)(gp);                                               \
    PF[1] = *(const uint2*)(gp + 256);                                         \
    PF[2] = *(const uint2*)(gp + 512); }

__global__ __attribute__((amdgpu_flat_work_group_size(NTHR, NTHR), amdgpu_waves_per_eu(2)))
void gru_l1dec(const float* __restrict__ bhh1, const float* __restrict__ Wdih,
               const float* __restrict__ bdih, const float* __restrict__ bdhh,
               const float* __restrict__ Wo, const float* __restrict__ bo,
               const __half* __restrict__ gi, float* __restrict__ outp) {
  __shared__ Smem sm;
  LANE_GEOM8
  DECL8
  const _Float16* wbase = wpk_g + 196608 + (size_t)w * 24576;  // layer 1
  const char* twp = (const char*)sm.tw + row * 4;
  const char* tbp = (const char*)sm.tb + row * 4;
  const char* wop = (const char*)sm.wo + row * 4;

  if (tid < 256) sm.bnh[tid] = bhh1[512 + tid];
  ((u32*)sm.h)[tid] = 0;
  LOADW(wA, 0) LOADW(wB, 1) LOADW(wC, 2) LOADW(wD, 3)
  __syncthreads();

  // ---------------- Phase 3: encoder GRU layer 1 ----------------
  int pb = 0;
#pragma unroll 1
  for (int t = 0; t < LSEQ; ++t) {
    uint2 pf[3];
    f32x4 pr, pz, pn;
    MCORE8(pb, LOADGI(pf, t))
    const __half2* p0 = (const __half2*)&pf[0];
    const __half2* p1 = (const __half2*)&pf[1];
    const __half2* p2 = (const __half2*)&pf[2];
    const float2 r01 = __half22float2(p0[0]), r23 = __half22float2(p0[1]);
    const float2 z01 = __half22float2(p1[0]), z23 = __half22float2(p1[1]);
    const float2 n01 = __half22float2(p2[0]), n23 = __half22float2(p2[1]);
    const f32x4 g_r = {r01.x, r01.y, r23.x, r23.y};
    const f32x4 g_z = {z01.x, z01.y, z23.x, z23.y};
    const f32x4 g_n = {n01.x, n01.y, n23.x, n23.y};
    GTAIL8(g_r, g_z, g_n, ;, ;)
    pb ^= 1;
    BAR;
  }

  // ---------------- Phase 4: autoregressive decoder (96 steps) --------------
  wbase = wpk_g + 2 * 196608 + (size_t)w * 24576;  // decoder layer
  if (tid < 256) {
#pragma unroll
    for (int g = 0; g < 3; ++g) {
      sm.tw[g][tid] = Wdih[256 * g + tid];
      sm.tb[g][tid] = bdih[256 * g + tid] + (g < 2 ? bdhh[256 * g + tid] : 0.f);
    }
    sm.bnh[tid] = bdhh[512 + tid];
    sm.wo[tid] = Wo[tid];
  }
  const float bov = bo[0];
  if (tid < 8) sm.red[0][tid] = (tid == 0) ? -bov : 0.f;  // it(0) == 0
  LOADW(wA, 0) LOADW(wB, 1) LOADW(wC, 2) LOADW(wD, 3)
  __syncthreads();                  // full drain + re-prime

  int rb = 0;
#pragma unroll 1
  for (int t = 0; t < PRED; ++t) {
    const f32x4 rd0 = *(const f32x4*)sm.red[rb];
    const f32x4 rd1 = *(const f32x4*)(&sm.red[rb][4]);
    const float it = bov + rd0[0] + rd0[1] + rd0[2] + rd0[3] +
                     rd1[0] + rd1[1] + rd1[2] + rd1[3];  // out(t-1)
    if (tid == 0 && t > 0) outp[(size_t)b * PRED + t - 1] = it;
    f32x4 pr, pz, pn;
    MCORE8(pb, ;)
    const f32x4 g_r = *(const f32x4*)twp * it + *(const f32x4*)tbp;
    const f32x4 g_z = *(const f32x4*)(twp + 1024) * it + *(const f32x4*)(tbp + 1024);
    const f32x4 g_n = *(const f32x4*)(twp + 2048) * it + *(const f32x4*)(tbp + 2048);
    const f32x4 wo4 = *(const f32x4*)wop;
    float c = 0.f;
    GTAIL8(g_r, g_z, g_n, c = fmaf(wo4[r], hv, c);, ;)
    if (!st) c = 0.f;
    c += __shfl_xor(c, 2);   // sum the 2 storer slots (n=0,2)
    c += __shfl_xor(c, 16);  // sum over q
    c += __shfl_xor(c, 32);
    if (lane == 0) sm.red[rb ^ 1][w] = c;
    pb ^= 1;
    rb ^= 1;
    BAR;
  }
  if (tid == 0) {
    float ov = bov;
#pragma unroll
    for (int ww = 0; ww < 8; ++ww) ov += sm.red[rb][ww];
    outp[(size_t)b * PRED + PRED - 1] = ov;
  }
}

extern "C" void kernel_launch(void* const* d_in, const int* in_sizes, int n_in,
                              void* d_out, int out_size, void* d_ws, size_t ws_size,
                              hipStream_t stream) {
  const float* x    = (const float*)d_in[0];
  const float* Wih0 = (const float*)d_in[1];
  const float* Whh0 = (const float*)d_in[2];
  const float* bih0 = (const float*)d_in[3];
  const float* bhh0 = (const float*)d_in[4];
  const float* Wih1 = (const float*)d_in[5];
  const float* Whh1 = (const float*)d_in[6];
  const float* bih1 = (const float*)d_in[7];
  const float* bhh1 = (const float*)d_in[8];
  const float* Wdih = (const float*)d_in[9];
  const float* Wdhh = (const float*)d_in[10];
  const float* bdih = (const float*)d_in[11];
  const float* bdhh = (const float*)d_in[12];
  const float* Wo   = (const float*)d_in[13];
  const float* bo   = (const float*)d_in[14];

  // ws layout: ys0 (f16, 64 MiB) | GI1 (f16, 192 MiB); weight pack lives in
  // the static device global wpk_g (no ws growth, no hipMalloc).
  __half* ys = (__half*)d_ws;
  __half* gi = ys + (size_t)256 * 512 * 256;

  prep<<<288, 256, 0, stream>>>(Whh0, Whh1, Wdhh);
  gru_l0<<<256, NTHR, 0, stream>>>(x, Wih0, bih0, bhh0, ys);
  gemm_gi<<<(256 * 512) / 16, 256, 0, stream>>>(Wih1, bih1, bhh1, ys, gi);
  gru_l1dec<<<256, NTHR, 0, stream>>>(bhh1, Wdih, bdih, bdhh, Wo, bo,
                                      gi, (float*)d_out);
}

// Round 11
// 3156.527 us; speedup vs baseline: 1.6221x; 1.6221x over previous
//
#include <hip/hip_runtime.h>
#include <hip/hip_fp16.h>

#define HDIM 256
#define LSEQ 512
#define PRED 96
#define NTHR 512  // 8 waves = 2/SIMD; wave w owns h-rows [32w, 32w+32)

typedef _Float16 f16x8 __attribute__((ext_vector_type(8)));
typedef _Float16 f16x4 __attribute__((ext_vector_type(4)));
typedef float f32x4 __attribute__((ext_vector_type(4)));
typedef unsigned int u32;

__device__ __forceinline__ float sigm(float x) { return 1.f / (1.f + __expf(-x)); }
__device__ __forceinline__ float tanh_(float x) { float t = __expf(2.f * x); return 1.f - 2.f / (t + 1.f); }
__device__ __forceinline__ float dppx1(float v) {
  return __builtin_bit_cast(float, __builtin_amdgcn_update_dpp(
      0, __builtin_bit_cast(int, v), 0xB1, 0xF, 0xF, true));
}

// One batch column per block, 256 blocks, 8 waves = 2/SIMD (256-reg budget).
// M-split (R8/R10-proven geometry): wave w owns 32 rows of each gate.
// Weights CU-RESIDENT (R10 lesson: L2-streaming needs 384KB/step/CU = 3.4x
// per-CU L2 BW — infeasible): r/z-gate tiles (tau0-3) in AGPR (128 regs),
// n-gate tiles (tau4,5) in LDS (16 tiles x 8KB = 128KB, dynamic LDS — the
// HipKittens 8-phase GEMM pattern proves >64KB plain-HIP LDS on gfx950).
// Sync: R5/R10-proven only — no explicit vmcnt; lgkm-only BAR (only ys
// stores ride, R5-proven); volatile MFMAs; acc reads ONLY after the full
// stream + 64cy fence (R6/R7 lesson).
struct __align__(16) DynS {
  _Float16 A[16][4096];   // [w*2+j][kt*512 + n*32 + q*8] n-gate f16 frags
  _Float16 h[2][2][256];  // [buf][hi/lo][row]: h split f16 hi+lo == f32
  float tw[3][256], tb[3][256], bnh[256], wo[256];
  float xv[LSEQ];
  float redd[2][8];       // decoder partial sums, double-buffered
};  // 143,424 B dynamic LDS

#define CAST_A(DST, SRC) asm("" : "=a"(DST) : "0"(SRC))

__device__ __forceinline__ f16x8 cvt8(const float* p) {
  const float4 a0 = *(const float4*)p;
  const float4 a1 = *(const float4*)(p + 4);
  f16x8 tf;
  tf[0] = (_Float16)a0.x; tf[1] = (_Float16)a0.y;
  tf[2] = (_Float16)a0.z; tf[3] = (_Float16)a0.w;
  tf[4] = (_Float16)a1.x; tf[5] = (_Float16)a1.y;
  tf[6] = (_Float16)a1.z; tf[7] = (_Float16)a1.w;
  return tf;
}

#define DECL8                                                                  \
  f32x4 ac[6];      /* 24 AGPR accumulators (tau = gate*2 + slot) */           \
  f32x4 zc;                                                                    \
  { f32x4 z4 = {0.f, 0.f, 0.f, 0.f}; asm("" : "=a"(zc) : "0"(z4)); }           \
  f16x8 Aa[4][8];   /* r/z weight frags, 128 AGPR */

// A-frag (m89/m91 layout, proven R4-R10): lane(n,q) holds row base+n,
// k = 32kt + 8q + i. Reg tiles tau 0-3 = gates r,z.
#define LOADA_REG(WPTR)                                                        \
  _Pragma("unroll") for (int tau = 0; tau < 4; ++tau)                          \
  _Pragma("unroll") for (int kt = 0; kt < 8; ++kt) {                           \
    const f16x8 tf = cvt8((WPTR) +                                             \
        (size_t)(256 * (tau >> 1) + 32 * w + 16 * (tau & 1) + n) * HDIM +      \
        32 * kt + 8 * q);                                                      \
    CAST_A(Aa[tau][kt], tf);                                                   \
  }

// n-gate tiles (g=2, slots j=0,1) staged to LDS; each wave stages its own 2.
#define STAGEA(WPTR)                                                           \
  _Pragma("unroll") for (int j = 0; j < 2; ++j)                                \
  _Pragma("unroll") for (int kt = 0; kt < 8; ++kt) {                           \
    const f16x8 tf = cvt8((WPTR) +                                             \
        (size_t)(512 + 32 * w + 16 * j + n) * HDIM + 32 * kt + 8 * q);         \
    *(f16x8*)(sm.A[w * 2 + j] + kt * 512 + n * 32 + q * 8) = tf;               \
  }

// volatile: pin MFMA program order
#define MM_A_S(I, AF, B) asm volatile("v_mfma_f32_16x16x32_f16 %0, %1, %2, %3" : "=a"(ac[I]) : "a"(AF), "v"(B), "a"(zc));
#define MM_A(I, AF, B)   asm volatile("v_mfma_f32_16x16x32_f16 %0, %1, %2, %0" : "+a"(ac[I]) : "a"(AF), "v"(B));
#define MM_V_S(I, AF, B) asm volatile("v_mfma_f32_16x16x32_f16 %0, %1, %2, %3" : "=a"(ac[I]) : "v"(AF), "v"(B), "a"(zc));
#define MM_V(I, AF, B)   asm volatile("v_mfma_f32_16x16x32_f16 %0, %1, %2, %0" : "+a"(ac[I]) : "v"(AF), "v"(B));

// one k-slice: B-frag u (parity=hi/lo pair trick) + 2 LDS A-frags + 6 MFMA.
// Loads are NOT volatile -> compiler hoists/prefetches them freely.
#define KQ_S(KT)                                                               \
  { const f16x8 u = *(const f16x8*)(hp + (KT) * 64);                           \
    const f16x8 l0 = *(const f16x8*)(aw0 + (KT) * 512);                        \
    const f16x8 l1 = *(const f16x8*)(aw1 + (KT) * 512);                        \
    MM_A_S(0, Aa[0][KT], u) MM_A_S(1, Aa[1][KT], u)                            \
    MM_A_S(2, Aa[2][KT], u) MM_A_S(3, Aa[3][KT], u)                            \
    MM_V_S(4, l0, u) MM_V_S(5, l1, u) }
#define KQ(KT)                                                                 \
  { const f16x8 u = *(const f16x8*)(hp + (KT) * 64);                           \
    const f16x8 l0 = *(const f16x8*)(aw0 + (KT) * 512);                        \
    const f16x8 l1 = *(const f16x8*)(aw1 + (KT) * 512);                        \
    MM_A(0, Aa[0][KT], u) MM_A(1, Aa[1][KT], u)                                \
    MM_A(2, Aa[2][KT], u) MM_A(3, Aa[3][KT], u)                                \
    MM_V(4, l0, u) MM_V(5, l1, u) }

// MFMA->VALU(accvgpr_read) fence AFTER the full stream (R10-proven, 64cy).
#define FENCE                                                                  \
  asm volatile("s_nop 7\n\ts_nop 7\n\ts_nop 7\n\ts_nop 7\n\t"                  \
               "s_nop 7\n\ts_nop 7\n\ts_nop 7\n\ts_nop 7"                      \
               : "+a"(ac[0]), "+a"(ac[1]), "+a"(ac[2]),                        \
                 "+a"(ac[3]), "+a"(ac[4]), "+a"(ac[5]));                       \
  __builtin_amdgcn_sched_barrier(0);

// lgkm-only barrier: LDS handoff ordered; ys global stores ride (R5-proven).
#define BAR asm volatile("s_waitcnt lgkmcnt(0)\n\ts_barrier" ::: "memory")

#define SELG2(P, G)                                                            \
  { const f32x4 e0 = ac[2 * (G)], e1 = ac[2 * (G) + 1]; P = s1 ? e1 : e0; }
#define PSUM(P)                                                                \
  { P[0] += dppx1(P[0]); P[1] += dppx1(P[1]);                                  \
    P[2] += dppx1(P[2]); P[3] += dppx1(P[3]); }

// D[768, hi|lo] = Whh*h: kt-major, 48 MFMA/wave (96/SIMD at 2 waves).
#define MCORE8(PB, ...)                                                        \
  {                                                                            \
    const char* hp = hq + (PB) * 1024;                                         \
    __VA_ARGS__                                                                \
    KQ_S(0) KQ(1) KQ(2) KQ(3) KQ(4) KQ(5) KQ(6) KQ(7)                          \
    FENCE                                                                      \
    SELG2(pr, 0) PSUM(pr)                                                      \
    SELG2(pz, 1) PSUM(pz)                                                      \
    SELG2(pn, 2) PSUM(pn)                                                      \
  }

// Gate math + h update for this lane's 4 rows; st lanes (n in {0,2}) store.
#define GTAIL8(GR, GZ, GN, RHOOK, STEXTRA)                                     \
  {                                                                            \
    const char* rh = hrow + pb * 1024;                                         \
    char* wh = hrow + (pb ^ 1) * 1024;                                         \
    const f16x4 hh = *(const f16x4*)rh;                                        \
    const f16x4 hl = *(const f16x4*)(rh + 512);                                \
    const f32x4 bn4 = *(const f32x4*)bnrow;                                    \
    f16x4 vh, vl;                                                              \
    _Pragma("unroll") for (int r = 0; r < 4; ++r) {                            \
      const float rr = sigm((GR)[r] + pr[r]);                                  \
      const float zz = sigm((GZ)[r] + pz[r]);                                  \
      const float nn = tanh_(fmaf(rr, pn[r] + bn4[r], (GN)[r]));               \
      const float ho = (float)hh[r] + (float)hl[r];                            \
      const float hv = fmaf(zz, ho - nn, nn);                                  \
      vh[r] = (_Float16)hv;                                                    \
      vl[r] = (_Float16)(hv - (float)vh[r]);                                   \
      RHOOK                                                                    \
    }                                                                          \
    if (st) {                                                                  \
      *(f16x4*)wh = vh;                                                        \
      *(f16x4*)(wh + 512) = vl;                                                \
      STEXTRA                                                                  \
    }                                                                          \
  }

#define LANE_GEOM8                                                             \
  const int tid = threadIdx.x;                                                 \
  const int w = tid >> 6, lane = tid & 63, n = lane & 15, q = lane >> 4;       \
  const int b = blockIdx.x;                                                    \
  const bool s1 = (n & 2) != 0;                                                \
  const bool st = (n & 13) == 0; /* n in {0,2}: unique (slot,q) storers */     \
  const int sg1 = (n >> 1) & 1;                                                \
  const int row = 32 * w + 16 * sg1 + 4 * q;                                   \
  const char* hq = (const char*)sm.h + (n & 1) * 512 + q * 16;                 \
  char* hrow = (char*)sm.h + row * 2;                                          \
  const char* bnrow = (const char*)sm.bnh + row * 4;                           \
  const _Float16* aw0 = sm.A[w * 2] + n * 32 + q * 8;                          \
  const _Float16* aw1 = sm.A[w * 2 + 1] + n * 32 + q * 8;

// =================== Kernel 1: encoder GRU layer 0 ===========================
__global__ __attribute__((amdgpu_flat_work_group_size(NTHR, NTHR), amdgpu_waves_per_eu(2, 2)))
void gru_l0(const float* __restrict__ x, const float* __restrict__ Wih0,
            const float* __restrict__ Whh0, const float* __restrict__ bih0,
            const float* __restrict__ bhh0, __half* __restrict__ ys) {
  extern __shared__ char smem_[];
  DynS& sm = *reinterpret_cast<DynS*>(smem_);
  LANE_GEOM8
  DECL8
  const char* twp = (const char*)sm.tw + row * 4;
  const char* tbp = (const char*)sm.tb + row * 4;

  sm.xv[tid] = x[(size_t)b * LSEQ + tid];
  if (tid < 256) {
#pragma unroll
    for (int g = 0; g < 3; ++g) {
      sm.tw[g][tid] = Wih0[256 * g + tid];
      sm.tb[g][tid] = bih0[256 * g + tid] + (g < 2 ? bhh0[256 * g + tid] : 0.f);
    }
    sm.bnh[tid] = bhh0[512 + tid];  // bhh_n: sits INSIDE the r-multiply
  }
  ((u32*)sm.h)[tid] = 0;            // zero both h buffers (2048 B)
  STAGEA(Whh0);
  LOADA_REG(Whh0);
  __syncthreads();

  __half* ysp = ys + (size_t)b * LSEQ * HDIM + row;
  int pb = 0;
#pragma unroll 1
  for (int t = 0; t < LSEQ; ++t) {
    const float xt = sm.xv[t];
    f32x4 pr, pz, pn;
    MCORE8(pb, ;)
    const f32x4 g_r = *(const f32x4*)twp * xt + *(const f32x4*)tbp;
    const f32x4 g_z = *(const f32x4*)(twp + 1024) * xt + *(const f32x4*)(tbp + 1024);
    const f32x4 g_n = *(const f32x4*)(twp + 2048) * xt + *(const f32x4*)(tbp + 2048);
    GTAIL8(g_r, g_z, g_n, ;, *(f16x4*)ysp = vh;)
    ysp += HDIM;
    pb ^= 1;
    BAR;
  }
}

// ===== Kernel 2: GI1 = ys0 @ W_ih1^T + (bih1 + bhh1_{r,z}) — MFMA GEMM ======
__global__ __launch_bounds__(256) void gemm_gi(
    const float* __restrict__ Wih1, const float* __restrict__ bih1,
    const float* __restrict__ bhh1, const __half* __restrict__ ys,
    __half* __restrict__ gi) {
  const int lane = threadIdx.x & 63;
  const int wv = threadIdx.x >> 6;
  const size_t bt0 = (size_t)blockIdx.x << 4;
  const int n = lane & 15, q = lane >> 4;

  f16x8 bfr[8];
  const __half* yrow = ys + (bt0 + n) * HDIM + q * 8;
#pragma unroll
  for (int kk = 0; kk < 8; ++kk) bfr[kk] = *(const f16x8*)(yrow + kk * 32);

#pragma unroll 1
  for (int mt = 0; mt < 12; ++mt) {
    const int j0 = (wv * 12 + mt) << 4;
    const float* arow = Wih1 + (size_t)(j0 + n) * HDIM + q * 8;
    f32x4 acc = {0.f, 0.f, 0.f, 0.f};
#pragma unroll
    for (int kk = 0; kk < 8; ++kk) {
      const f16x8 af = cvt8(arow + kk * 32);
      acc = __builtin_amdgcn_mfma_f32_16x16x32_f16(af, bfr[kk], acc, 0, 0, 0);
    }
    const int jr = j0 + (q << 2);
    __half o4[4];
#pragma unroll
    for (int r2 = 0; r2 < 4; ++r2) {
      const float bb = bih1[jr + r2] + (j0 < 512 ? bhh1[jr + r2] : 0.f);
      o4[r2] = __float2half(acc[r2] + bb);
    }
    *(uint2*)(gi + (bt0 + n) * 768 + jr) = *(uint2*)o4;
  }
}

// ====== Kernel 3: encoder GRU layer 1 (gi-driven) + autoregressive decoder ===
// Per-step gi load issued at stream top (hook), consumed after the full
// stream — compiler-managed waits, nothing rides across barriers (R10-safe).
#define LOADGI(PF, T)                                                          \
  { const __half* gp = gi + ((size_t)b * LSEQ + (T)) * 768 + row;              \
    PF[0] = *(const uint2*)(gp);                                               \
    PF[1] = *(const uint2*)(gp + 256);                                         \
    PF[2] = *(const uint2*)(gp + 512); }

__global__ __attribute__((amdgpu_flat_work_group_size(NTHR, NTHR), amdgpu_waves_per_eu(2, 2)))
void gru_l1dec(const float* __restrict__ Whh1, const float* __restrict__ bhh1,
               const float* __restrict__ Wdih, const float* __restrict__ Wdhh,
               const float* __restrict__ bdih, const float* __restrict__ bdhh,
               const float* __restrict__ Wo, const float* __restrict__ bo,
               const __half* __restrict__ gi, float* __restrict__ outp) {
  extern __shared__ char smem_[];
  DynS& sm = *reinterpret_cast<DynS*>(smem_);
  LANE_GEOM8
  DECL8
  const char* twp = (const char*)sm.tw + row * 4;
  const char* tbp = (const char*)sm.tb + row * 4;
  const char* wop = (const char*)sm.wo + row * 4;

  if (tid < 256) sm.bnh[tid] = bhh1[512 + tid];
  ((u32*)sm.h)[tid] = 0;
  STAGEA(Whh1);
  LOADA_REG(Whh1);
  __syncthreads();

  // ---------------- Phase 3: encoder GRU layer 1 ----------------
  int pb = 0;
#pragma unroll 1
  for (int t = 0; t < LSEQ; ++t) {
    uint2 pf[3];
    f32x4 pr, pz, pn;
    MCORE8(pb, LOADGI(pf, t))
    const __half2* p0 = (const __half2*)&pf[0];
    const __half2* p1 = (const __half2*)&pf[1];
    const __half2* p2 = (const __half2*)&pf[2];
    const float2 r01 = __half22float2(p0[0]), r23 = __half22float2(p0[1]);
    const float2 z01 = __half22float2(p1[0]), z23 = __half22float2(p1[1]);
    const float2 n01 = __half22float2(p2[0]), n23 = __half22float2(p2[1]);
    const f32x4 g_r = {r01.x, r01.y, r23.x, r23.y};
    const f32x4 g_z = {z01.x, z01.y, z23.x, z23.y};
    const f32x4 g_n = {n01.x, n01.y, n23.x, n23.y};
    GTAIL8(g_r, g_z, g_n, ;, ;)
    pb ^= 1;
    BAR;
  }

  // ---------------- Phase 4: autoregressive decoder (96 steps) --------------
  const float bov = bo[0];
  STAGEA(Wdhh);
  LOADA_REG(Wdhh);
  if (tid < 256) {
#pragma unroll
    for (int g = 0; g < 3; ++g) {
      sm.tw[g][tid] = Wdih[256 * g + tid];
      sm.tb[g][tid] = bdih[256 * g + tid] + (g < 2 ? bdhh[256 * g + tid] : 0.f);
    }
    sm.bnh[tid] = bdhh[512 + tid];
    sm.wo[tid] = Wo[tid];
  }
  if (tid < 8) sm.redd[0][tid] = (tid == 0) ? -bov : 0.f;  // it(0) == 0
  __syncthreads();

  int rb = 0;
#pragma unroll 1
  for (int t = 0; t < PRED; ++t) {
    const f32x4 rd0 = *(const f32x4*)sm.redd[rb];
    const f32x4 rd1 = *(const f32x4*)(&sm.redd[rb][4]);
    const float it = bov + rd0[0] + rd0[1] + rd0[2] + rd0[3] +
                     rd1[0] + rd1[1] + rd1[2] + rd1[3];  // out(t-1)
    if (tid == 0 && t > 0) outp[(size_t)b * PRED + t - 1] = it;
    f32x4 pr, pz, pn;
    MCORE8(pb, ;)
    const f32x4 g_r = *(const f32x4*)twp * it + *(const f32x4*)tbp;
    const f32x4 g_z = *(const f32x4*)(twp + 1024) * it + *(const f32x4*)(tbp + 1024);
    const f32x4 g_n = *(const f32x4*)(twp + 2048) * it + *(const f32x4*)(tbp + 2048);
    const f32x4 wo4 = *(const f32x4*)wop;
    float c = 0.f;
    GTAIL8(g_r, g_z, g_n, c = fmaf(wo4[r], hv, c);, ;)
    if (!st) c = 0.f;
    c += __shfl_xor(c, 2);   // sum the 2 storer slots (n=0,2)
    c += __shfl_xor(c, 16);  // sum over q
    c += __shfl_xor(c, 32);
    if (lane == 0) sm.redd[rb ^ 1][w] = c;
    pb ^= 1;
    rb ^= 1;
    BAR;
  }
  if (tid == 0) {
    float ov = bov;
#pragma unroll
    for (int ww = 0; ww < 8; ++ww) ov += sm.redd[rb][ww];
    outp[(size_t)b * PRED + PRED - 1] = ov;
  }
}

extern "C" void kernel_launch(void* const* d_in, const int* in_sizes, int n_in,
                              void* d_out, int out_size, void* d_ws, size_t ws_size,
                              hipStream_t stream) {
  const float* x    = (const float*)d_in[0];
  const float* Wih0 = (const float*)d_in[1];
  const float* Whh0 = (const float*)d_in[2];
  const float* bih0 = (const float*)d_in[3];
  const float* bhh0 = (const float*)d_in[4];
  const float* Wih1 = (const float*)d_in[5];
  const float* Whh1 = (const float*)d_in[6];
  const float* bih1 = (const float*)d_in[7];
  const float* bhh1 = (const float*)d_in[8];
  const float* Wdih = (const float*)d_in[9];
  const float* Wdhh = (const float*)d_in[10];
  const float* bdih = (const float*)d_in[11];
  const float* bdhh = (const float*)d_in[12];
  const float* Wo   = (const float*)d_in[13];
  const float* bo   = (const float*)d_in[14];

  // ws layout: ys0 (f16, 64 MiB) | GI1 (f16, 192 MiB)
  __half* ys = (__half*)d_ws;
  __half* gi = ys + (size_t)256 * 512 * 256;

  // opt-in to >64KB dynamic LDS (one-time; not a stream op — capture-safe)
  static int attr_done = 0;
  if (!attr_done) {
    (void)hipFuncSetAttribute((const void*)gru_l0,
        hipFuncAttributeMaxDynamicSharedMemorySize, (int)sizeof(DynS));
    (void)hipFuncSetAttribute((const void*)gru_l1dec,
        hipFuncAttributeMaxDynamicSharedMemorySize, (int)sizeof(DynS));
    attr_done = 1;
  }

  gru_l0<<<256, NTHR, sizeof(DynS), stream>>>(x, Wih0, Whh0, bih0, bhh0, ys);
  gemm_gi<<<(256 * 512) / 16, 256, 0, stream>>>(Wih1, bih1, bhh1, ys, gi);
  gru_l1dec<<<256, NTHR, sizeof(DynS), stream>>>(Whh1, bhh1, Wdih, Wdhh,
                                                 bdih, bdhh, Wo, bo, gi,
                                                 (float*)d_out);
}

// Round 12
// 2646.463 us; speedup vs baseline: 1.9348x; 1.1927x over previous
//
#include <hip/hip_runtime.h>
#include <hip/hip_fp16.h>

#define HDIM 256
#define LSEQ 512
#define PRED 96
#define NTHR 512  // 8 waves = 2/SIMD; wave w owns h-rows [32w, 32w+32)

typedef _Float16 f16x8 __attribute__((ext_vector_type(8)));
typedef _Float16 f16x2 __attribute__((ext_vector_type(2)));
typedef float f32x4 __attribute__((ext_vector_type(4)));
typedef float f32x2 __attribute__((ext_vector_type(2)));
typedef unsigned int u32;

__device__ __forceinline__ float sigm(float x) { return 1.f / (1.f + __expf(-x)); }
__device__ __forceinline__ float tanh_(float x) { float t = __expf(2.f * x); return 1.f - 2.f / (t + 1.f); }
__device__ __forceinline__ float dppx1(float v) {
  return __builtin_bit_cast(float, __builtin_amdgcn_update_dpp(
      0, __builtin_bit_cast(int, v), 0xB1, 0xF, 0xF, true));
}
__device__ __forceinline__ f32x2 cvt2f(u32 v) {
  const __half2 h = __builtin_bit_cast(__half2, v);
  const float2 f = __half22float2(h);
  f32x2 r; r[0] = f.x; r[1] = f.y; return r;
}

// One batch column per block, 256 blocks, 8 waves = 2/SIMD (256-reg budget).
// Weights CU-resident: r/z tiles in AGPR (128), n-gate tiles in dynamic LDS
// (128KB). R12 vs R11 (passed, 3156us):
//  (1) A-tile XOR-swizzle (slot q^=(n>>1)&3, BOTH stage and read — rule #21):
//      R11's n*64+q*16 banked as 16(n&1)+4q = 8-way conflict (1.2e8 counter).
//  (2) r-pair split (n&4 picks acc elem pair): each lane gates 2 rows not 4
//      — halves the gate-tail VALU that two lockstep waves serialize on.
// Sync/numerics identical to R11: lgkm-only BAR, volatile MFMAs, acc reads
// only after full stream + 64cy fence.
struct __align__(16) DynS {
  _Float16 A[16][4096];   // [w*2+j][kt*512 + n*32 + qs*8] n-gate frags (swz)
  _Float16 h[2][2][256];  // [buf][hi/lo][row]: h split f16 hi+lo == f32
  float tw[3][256], tb[3][256], bnh[256], wo[256];
  float xv[LSEQ];
  float redd[2][8];       // decoder partial sums, double-buffered
};  // 143,424 B dynamic LDS

#define CAST_A(DST, SRC) asm("" : "=a"(DST) : "0"(SRC))

__device__ __forceinline__ f16x8 cvt8(const float* p) {
  const float4 a0 = *(const float4*)p;
  const float4 a1 = *(const float4*)(p + 4);
  f16x8 tf;
  tf[0] = (_Float16)a0.x; tf[1] = (_Float16)a0.y;
  tf[2] = (_Float16)a0.z; tf[3] = (_Float16)a0.w;
  tf[4] = (_Float16)a1.x; tf[5] = (_Float16)a1.y;
  tf[6] = (_Float16)a1.z; tf[7] = (_Float16)a1.w;
  return tf;
}

#define DECL8                                                                  \
  f32x4 ac[6];      /* 24 AGPR accumulators (tau = gate*2 + slot) */           \
  f32x4 zc;                                                                    \
  { f32x4 z4 = {0.f, 0.f, 0.f, 0.f}; asm("" : "=a"(zc) : "0"(z4)); }           \
  f16x8 Aa[4][8];   /* r/z weight frags, 128 AGPR */

// A-frag (m89/m91 layout, proven R4-R11): lane(n,q) holds row base+n,
// k = 32kt + 8q + i. Reg tiles tau 0-3 = gates r,z.
#define LOADA_REG(WPTR)                                                        \
  _Pragma("unroll") for (int tau = 0; tau < 4; ++tau)                          \
  _Pragma("unroll") for (int kt = 0; kt < 8; ++kt) {                           \
    const f16x8 tf = cvt8((WPTR) +                                             \
        (size_t)(256 * (tau >> 1) + 32 * w + 16 * (tau & 1) + n) * HDIM +      \
        32 * kt + 8 * q);                                                      \
    CAST_A(Aa[tau][kt], tf);                                                   \
  }

// n-gate tiles staged to LDS at the SWIZZLED slot (same formula as read).
#define STAGEA(WPTR)                                                           \
  _Pragma("unroll") for (int j = 0; j < 2; ++j)                                \
  _Pragma("unroll") for (int kt = 0; kt < 8; ++kt) {                           \
    const f16x8 tf = cvt8((WPTR) +                                             \
        (size_t)(512 + 32 * w + 16 * j + n) * HDIM + 32 * kt + 8 * q);         \
    *(f16x8*)(sm.A[w * 2 + j] + kt * 512 + n * 32 + qs * 8) = tf;              \
  }

// volatile: pin MFMA program order
#define MM_A_S(I, AF, B) asm volatile("v_mfma_f32_16x16x32_f16 %0, %1, %2, %3" : "=a"(ac[I]) : "a"(AF), "v"(B), "a"(zc));
#define MM_A(I, AF, B)   asm volatile("v_mfma_f32_16x16x32_f16 %0, %1, %2, %0" : "+a"(ac[I]) : "a"(AF), "v"(B));
#define MM_V_S(I, AF, B) asm volatile("v_mfma_f32_16x16x32_f16 %0, %1, %2, %3" : "=a"(ac[I]) : "v"(AF), "v"(B), "a"(zc));
#define MM_V(I, AF, B)   asm volatile("v_mfma_f32_16x16x32_f16 %0, %1, %2, %0" : "+a"(ac[I]) : "v"(AF), "v"(B));

// one k-slice: B-frag u (parity=hi/lo pair trick) + 2 swizzled LDS A-frags.
#define KQ_S(KT)                                                               \
  { const f16x8 u = *(const f16x8*)(hp + (KT) * 64);                           \
    const f16x8 l0 = *(const f16x8*)(aw0 + (KT) * 512);                        \
    const f16x8 l1 = *(const f16x8*)(aw1 + (KT) * 512);                        \
    MM_A_S(0, Aa[0][KT], u) MM_A_S(1, Aa[1][KT], u)                            \
    MM_A_S(2, Aa[2][KT], u) MM_A_S(3, Aa[3][KT], u)                            \
    MM_V_S(4, l0, u) MM_V_S(5, l1, u) }
#define KQ(KT)                                                                 \
  { const f16x8 u = *(const f16x8*)(hp + (KT) * 64);                           \
    const f16x8 l0 = *(const f16x8*)(aw0 + (KT) * 512);                        \
    const f16x8 l1 = *(const f16x8*)(aw1 + (KT) * 512);                        \
    MM_A(0, Aa[0][KT], u) MM_A(1, Aa[1][KT], u)                                \
    MM_A(2, Aa[2][KT], u) MM_A(3, Aa[3][KT], u)                                \
    MM_V(4, l0, u) MM_V(5, l1, u) }

// MFMA->VALU(accvgpr_read) fence AFTER the full stream (proven, 64cy).
#define FENCE                                                                  \
  asm volatile("s_nop 7\n\ts_nop 7\n\ts_nop 7\n\ts_nop 7\n\t"                  \
               "s_nop 7\n\ts_nop 7\n\ts_nop 7\n\ts_nop 7"                      \
               : "+a"(ac[0]), "+a"(ac[1]), "+a"(ac[2]),                        \
                 "+a"(ac[3]), "+a"(ac[4]), "+a"(ac[5]));                       \
  __builtin_amdgcn_sched_barrier(0);

// lgkm-only barrier: LDS handoff ordered; ys global stores ride (proven).
#define BAR asm volatile("s_waitcnt lgkmcnt(0)\n\ts_barrier" ::: "memory")

// select this lane's 2 accumulator elements (tile s1, elem-pair s2) + PSUM
#define SELP(P, G)                                                             \
  { const f32x4 e0 = ac[2 * (G)], e1 = ac[2 * (G) + 1];                        \
    const f32x4 t = s1 ? e1 : e0;                                              \
    P[0] = s2 ? t[2] : t[0];                                                   \
    P[1] = s2 ? t[3] : t[1]; }
#define PSUM2(P) { P[0] += dppx1(P[0]); P[1] += dppx1(P[1]); }

// D[768, hi|lo] = Whh*h: kt-major, 48 MFMA/wave (96/SIMD at 2 waves).
#define MCORE8(PB, ...)                                                        \
  {                                                                            \
    const char* hp = hq + (PB) * 1024;                                         \
    __VA_ARGS__                                                                \
    KQ_S(0) KQ(1) KQ(2) KQ(3) KQ(4) KQ(5) KQ(6) KQ(7)                          \
    FENCE                                                                      \
    SELP(pr, 0) PSUM2(pr)                                                      \
    SELP(pz, 1) PSUM2(pz)                                                      \
    SELP(pn, 2) PSUM2(pn)                                                      \
  }

// Gate math + h update for this lane's 2 rows; st lanes (n in {0,2,4,6})
// store f16x2 hi+lo.
#define GTAIL8(GR, GZ, GN, RHOOK, STEXTRA)                                     \
  {                                                                            \
    const char* rh = hrow + pb * 1024;                                         \
    char* wh = hrow + (pb ^ 1) * 1024;                                         \
    const f16x2 hh = *(const f16x2*)rh;                                        \
    const f16x2 hl = *(const f16x2*)(rh + 512);                                \
    const f32x2 bn2 = *(const f32x2*)bnrow;                                    \
    f16x2 vh, vl;                                                              \
    _Pragma("unroll") for (int r = 0; r < 2; ++r) {                            \
      const float rr = sigm((GR)[r] + pr[r]);                                  \
      const float zz = sigm((GZ)[r] + pz[r]);                                  \
      const float nn = tanh_(fmaf(rr, pn[r] + bn2[r], (GN)[r]));               \
      const float ho = (float)hh[r] + (float)hl[r];                            \
      const float hv = fmaf(zz, ho - nn, nn);                                  \
      vh[r] = (_Float16)hv;                                                    \
      vl[r] = (_Float16)(hv - (float)vh[r]);                                   \
      RHOOK                                                                    \
    }                                                                          \
    if (st) {                                                                  \
      *(f16x2*)wh = vh;                                                        \
      *(f16x2*)(wh + 512) = vl;                                                \
      STEXTRA                                                                  \
    }                                                                          \
  }

#define LANE_GEOM8                                                             \
  const int tid = threadIdx.x;                                                 \
  const int w = tid >> 6, lane = tid & 63, n = lane & 15, q = lane >> 4;       \
  const int b = blockIdx.x;                                                    \
  const bool s1 = (n & 2) != 0;  /* tile-slot select */                        \
  const bool s2 = (n & 4) != 0;  /* elem-pair (r-pair) select */               \
  const bool st = (n & 9) == 0;  /* n in {0,2,4,6}: unique (slot,pair,q) */    \
  const int sg1 = (n >> 1) & 1;                                                \
  const int rp = (n >> 2) & 1;                                                 \
  const int row = 32 * w + 16 * sg1 + 4 * q;                                   \
  const int qs = q ^ ((n >> 1) & 3); /* A-tile bank swizzle slot */            \
  const char* hq = (const char*)sm.h + (n & 1) * 512 + q * 16;                 \
  char* hrow = (char*)sm.h + row * 2 + rp * 4;                                 \
  const char* bnrow = (const char*)sm.bnh + row * 4 + rp * 8;                  \
  const _Float16* aw0 = sm.A[w * 2] + n * 32 + qs * 8;                         \
  const _Float16* aw1 = sm.A[w * 2 + 1] + n * 32 + qs * 8;

// =================== Kernel 1: encoder GRU layer 0 ===========================
__global__ __attribute__((amdgpu_flat_work_group_size(NTHR, NTHR), amdgpu_waves_per_eu(2, 2)))
void gru_l0(const float* __restrict__ x, const float* __restrict__ Wih0,
            const float* __restrict__ Whh0, const float* __restrict__ bih0,
            const float* __restrict__ bhh0, __half* __restrict__ ys) {
  extern __shared__ char smem_[];
  DynS& sm = *reinterpret_cast<DynS*>(smem_);
  LANE_GEOM8
  DECL8
  const char* twp = (const char*)sm.tw + row * 4 + rp * 8;
  const char* tbp = (const char*)sm.tb + row * 4 + rp * 8;

  sm.xv[tid] = x[(size_t)b * LSEQ + tid];
  if (tid < 256) {
#pragma unroll
    for (int g = 0; g < 3; ++g) {
      sm.tw[g][tid] = Wih0[256 * g + tid];
      sm.tb[g][tid] = bih0[256 * g + tid] + (g < 2 ? bhh0[256 * g + tid] : 0.f);
    }
    sm.bnh[tid] = bhh0[512 + tid];  // bhh_n: sits INSIDE the r-multiply
  }
  ((u32*)sm.h)[tid] = 0;            // zero both h buffers (2048 B)
  STAGEA(Whh0);
  LOADA_REG(Whh0);
  __syncthreads();

  _Float16* ysp = (_Float16*)ys + (size_t)b * LSEQ * HDIM + row + rp * 2;
  int pb = 0;
#pragma unroll 1
  for (int t = 0; t < LSEQ; ++t) {
    const float xt = sm.xv[t];
    f32x2 pr, pz, pn;
    MCORE8(pb, ;)
    const f32x2 g_r = *(const f32x2*)twp * xt + *(const f32x2*)tbp;
    const f32x2 g_z = *(const f32x2*)(twp + 1024) * xt + *(const f32x2*)(tbp + 1024);
    const f32x2 g_n = *(const f32x2*)(twp + 2048) * xt + *(const f32x2*)(tbp + 2048);
    GTAIL8(g_r, g_z, g_n, ;, *(f16x2*)ysp = vh;)
    ysp += HDIM;
    pb ^= 1;
    BAR;
  }
}

// ===== Kernel 2: GI1 = ys0 @ W_ih1^T + (bih1 + bhh1_{r,z}) — MFMA GEMM ======
__global__ __launch_bounds__(256) void gemm_gi(
    const float* __restrict__ Wih1, const float* __restrict__ bih1,
    const float* __restrict__ bhh1, const __half* __restrict__ ys,
    __half* __restrict__ gi) {
  const int lane = threadIdx.x & 63;
  const int wv = threadIdx.x >> 6;
  const size_t bt0 = (size_t)blockIdx.x << 4;
  const int n = lane & 15, q = lane >> 4;

  f16x8 bfr[8];
  const __half* yrow = ys + (bt0 + n) * HDIM + q * 8;
#pragma unroll
  for (int kk = 0; kk < 8; ++kk) bfr[kk] = *(const f16x8*)(yrow + kk * 32);

#pragma unroll 1
  for (int mt = 0; mt < 12; ++mt) {
    const int j0 = (wv * 12 + mt) << 4;
    const float* arow = Wih1 + (size_t)(j0 + n) * HDIM + q * 8;
    f32x4 acc = {0.f, 0.f, 0.f, 0.f};
#pragma unroll
    for (int kk = 0; kk < 8; ++kk) {
      const f16x8 af = cvt8(arow + kk * 32);
      acc = __builtin_amdgcn_mfma_f32_16x16x32_f16(af, bfr[kk], acc, 0, 0, 0);
    }
    const int jr = j0 + (q << 2);
    __half o4[4];
#pragma unroll
    for (int r2 = 0; r2 < 4; ++r2) {
      const float bb = bih1[jr + r2] + (j0 < 512 ? bhh1[jr + r2] : 0.f);
      o4[r2] = __float2half(acc[r2] + bb);
    }
    *(uint2*)(gi + (bt0 + n) * 768 + jr) = *(uint2*)o4;
  }
}

// ====== Kernel 3: encoder GRU layer 1 (gi-driven) + autoregressive decoder ===
// Per-step gi u32 loads (this lane's 2 rows) issued at stream top, consumed
// after the full stream — compiler-managed waits (R11-proven pattern).
#define LOADGI(PF, T)                                                          \
  { const __half* gp = gi + ((size_t)b * LSEQ + (T)) * 768 + row + rp * 2;     \
    PF[0] = *(const u32*)(gp);                                                 \
    PF[1] = *(const u32*)(gp + 256);                                           \
    PF[2] = *(const u32*)(gp + 512); }

__global__ __attribute__((amdgpu_flat_work_group_size(NTHR, NTHR), amdgpu_waves_per_eu(2, 2)))
void gru_l1dec(const float* __restrict__ Whh1, const float* __restrict__ bhh1,
               const float* __restrict__ Wdih, const float* __restrict__ Wdhh,
               const float* __restrict__ bdih, const float* __restrict__ bdhh,
               const float* __restrict__ Wo, const float* __restrict__ bo,
               const __half* __restrict__ gi, float* __restrict__ outp) {
  extern __shared__ char smem_[];
  DynS& sm = *reinterpret_cast<DynS*>(smem_);
  LANE_GEOM8
  DECL8
  const char* twp = (const char*)sm.tw + row * 4 + rp * 8;
  const char* tbp = (const char*)sm.tb + row * 4 + rp * 8;
  const char* wop = (const char*)sm.wo + row * 4 + rp * 8;

  if (tid < 256) sm.bnh[tid] = bhh1[512 + tid];
  ((u32*)sm.h)[tid] = 0;
  STAGEA(Whh1);
  LOADA_REG(Whh1);
  __syncthreads();

  // ---------------- Phase 3: encoder GRU layer 1 ----------------
  int pb = 0;
#pragma unroll 1
  for (int t = 0; t < LSEQ; ++t) {
    u32 pf[3];
    f32x2 pr, pz, pn;
    MCORE8(pb, LOADGI(pf, t))
    const f32x2 g_r = cvt2f(pf[0]);
    const f32x2 g_z = cvt2f(pf[1]);
    const f32x2 g_n = cvt2f(pf[2]);
    GTAIL8(g_r, g_z, g_n, ;, ;)
    pb ^= 1;
    BAR;
  }

  // ---------------- Phase 4: autoregressive decoder (96 steps) --------------
  const float bov = bo[0];
  STAGEA(Wdhh);
  LOADA_REG(Wdhh);
  if (tid < 256) {
#pragma unroll
    for (int g = 0; g < 3; ++g) {
      sm.tw[g][tid] = Wdih[256 * g + tid];
      sm.tb[g][tid] = bdih[256 * g + tid] + (g < 2 ? bdhh[256 * g + tid] : 0.f);
    }
    sm.bnh[tid] = bdhh[512 + tid];
    sm.wo[tid] = Wo[tid];
  }
  if (tid < 8) sm.redd[0][tid] = (tid == 0) ? -bov : 0.f;  // it(0) == 0
  __syncthreads();

  int rb = 0;
#pragma unroll 1
  for (int t = 0; t < PRED; ++t) {
    const f32x4 rd0 = *(const f32x4*)sm.redd[rb];
    const f32x4 rd1 = *(const f32x4*)(&sm.redd[rb][4]);
    const float it = bov + rd0[0] + rd0[1] + rd0[2] + rd0[3] +
                     rd1[0] + rd1[1] + rd1[2] + rd1[3];  // out(t-1)
    if (tid == 0 && t > 0) outp[(size_t)b * PRED + t - 1] = it;
    f32x2 pr, pz, pn;
    MCORE8(pb, ;)
    const f32x2 g_r = *(const f32x2*)twp * it + *(const f32x2*)tbp;
    const f32x2 g_z = *(const f32x2*)(twp + 1024) * it + *(const f32x2*)(tbp + 1024);
    const f32x2 g_n = *(const f32x2*)(twp + 2048) * it + *(const f32x2*)(tbp + 2048);
    const f32x2 wo2 = *(const f32x2*)wop;
    float c = 0.f;
    GTAIL8(g_r, g_z, g_n, c = fmaf(wo2[r], hv, c);, ;)
    if (!st) c = 0.f;
    c += __shfl_xor(c, 2);   // merge tile-slot lanes (n&2)
    c += __shfl_xor(c, 4);   // merge r-pair lanes (n&4)
    c += __shfl_xor(c, 16);  // merge q
    c += __shfl_xor(c, 32);
    if (lane == 0) sm.redd[rb ^ 1][w] = c;
    pb ^= 1;
    rb ^= 1;
    BAR;
  }
  if (tid == 0) {
    float ov = bov;
#pragma unroll
    for (int ww = 0; ww < 8; ++ww) ov += sm.redd[rb][ww];
    outp[(size_t)b * PRED + PRED - 1] = ov;
  }
}

extern "C" void kernel_launch(void* const* d_in, const int* in_sizes, int n_in,
                              void* d_out, int out_size, void* d_ws, size_t ws_size,
                              hipStream_t stream) {
  const float* x    = (const float*)d_in[0];
  const float* Wih0 = (const float*)d_in[1];
  const float* Whh0 = (const float*)d_in[2];
  const float* bih0 = (const float*)d_in[3];
  const float* bhh0 = (const float*)d_in[4];
  const float* Wih1 = (const float*)d_in[5];
  const float* Whh1 = (const float*)d_in[6];
  const float* bih1 = (const float*)d_in[7];
  const float* bhh1 = (const float*)d_in[8];
  const float* Wdih = (const float*)d_in[9];
  const float* Wdhh = (const float*)d_in[10];
  const float* bdih = (const float*)d_in[11];
  const float* bdhh = (const float*)d_in[12];
  const float* Wo   = (const float*)d_in[13];
  const float* bo   = (const float*)d_in[14];

  // ws layout: ys0 (f16, 64 MiB) | GI1 (f16, 192 MiB)
  __half* ys = (__half*)d_ws;
  __half* gi = ys + (size_t)256 * 512 * 256;

  // opt-in to >64KB dynamic LDS (one-time; capture-safe — R11-proven)
  static int attr_done = 0;
  if (!attr_done) {
    (void)hipFuncSetAttribute((const void*)gru_l0,
        hipFuncAttributeMaxDynamicSharedMemorySize, (int)sizeof(DynS));
    (void)hipFuncSetAttribute((const void*)gru_l1dec,
        hipFuncAttributeMaxDynamicSharedMemorySize, (int)sizeof(DynS));
    attr_done = 1;
  }

  gru_l0<<<256, NTHR, sizeof(DynS), stream>>>(x, Wih0, Whh0, bih0, bhh0, ys);
  gemm_gi<<<(256 * 512) / 16, 256, 0, stream>>>(Wih1, bih1, bhh1, ys, gi);
  gru_l1dec<<<256, NTHR, sizeof(DynS), stream>>>(Whh1, bhh1, Wdih, Wdhh,
                                                 bdih, bdhh, Wo, bo, gi,
                                                 (float*)d_out);
}